// Round 8
// baseline (10702.576 us; speedup 1.0000x reference)
//
#include <hip/hip_runtime.h>
#include <math.h>

#define T_STEPS 1024
#define NB 128
#define D_IN 512
#define D_H 1024
#define K_TOT 1536
#define N_A 3072   // packed rows: [0,1024)=uW, [1024,2048)=gW_x, [2048,3072)=aW_x
#define N_H 2048   // packed rows: group g (j in [16g,16g+16)): 16 g-rows then 16 a-rows

typedef __bf16 bf16x8 __attribute__((ext_vector_type(8)));
typedef float f32x4 __attribute__((ext_vector_type(4)));
typedef unsigned long long u64;

__device__ __forceinline__ unsigned short f2bf(float f) {
    unsigned int u = __float_as_uint(f);
    unsigned int r = 0x7fffu + ((u >> 16) & 1u);
    return (unsigned short)((u + r) >> 16);
}
__device__ __forceinline__ float bf2f(unsigned short v) {
    return __uint_as_float(((unsigned int)v) << 16);
}
__device__ __forceinline__ float fast_tanh(float x) {
    float ax = fabsf(x);
    float e = __expf(2.0f * ax);
    float t = 1.0f - 2.0f / (e + 1.0f);
    return copysignf(t, x);
}
__device__ __forceinline__ bf16x8 cvt8(uint4 v) {
    union { uint4 u; bf16x8 b; } c; c.u = v; return c.b;
}

// ---------------- one-time packing / init ----------------

__global__ __launch_bounds__(256) void pack_wa(
    const float* __restrict__ uW, const float* __restrict__ gW,
    const float* __restrict__ aW, unsigned short* __restrict__ wa) {
    int i = blockIdx.x * 256 + threadIdx.x;          // N_A * D_IN
    if (i >= N_A * D_IN) return;
    int rr = i >> 9, k = i & 511;
    float v;
    if (rr < 1024)       v = uW[(size_t)rr * D_IN + k];
    else if (rr < 2048)  v = gW[(size_t)(rr - 1024) * K_TOT + k];
    else                 v = aW[(size_t)(rr - 2048) * K_TOT + k];
    wa[i] = f2bf(v);
}

__global__ __launch_bounds__(256) void pack_wh(
    const float* __restrict__ gW, const float* __restrict__ aW,
    unsigned short* __restrict__ wh) {
    int i = blockIdx.x * 256 + threadIdx.x;          // N_H * D_H
    if (i >= N_H * D_H) return;
    int rr = i >> 10, k = i & 1023;
    int g = rr >> 5, ii = rr & 31, j = g * 16 + (ii & 15);
    const float* src = (ii < 16) ? gW : aW;
    wh[i] = f2bf(src[(size_t)j * K_TOT + D_IN + k]);
}

__global__ __launch_bounds__(256) void rwa_init(
    const float* __restrict__ init_st, float* __restrict__ nbuf,
    float* __restrict__ dbuf, unsigned short* __restrict__ hbuf,
    int* __restrict__ flags) {
    int i = blockIdx.x * 256 + threadIdx.x;          // NB * D_H
    if (i >= NB * D_H) return;
    nbuf[i] = 0.f; dbuf[i] = 0.f;
    hbuf[i] = f2bf(tanhf(init_st[i & (D_H - 1)]));   // parity-0 buffer
    if (i < 512) flags[i] = 0;
}

// ---------------- phase A: pre_t = bf16( x_chunk @ W_A^T + bias ) ----------------
// output layout TRANSPOSED per step: pre[tl][n=3072][b=128] bf16

__global__ __launch_bounds__(256) void phase_a(
    const float* __restrict__ x, const unsigned short* __restrict__ wa,
    const float* __restrict__ ub, const float* __restrict__ gb,
    unsigned short* __restrict__ pre)
{
    __shared__ unsigned short As[128][72];
    __shared__ unsigned short Bs[128][72];
    const int tid = threadIdx.x;
    const int bn = blockIdx.x;           // 0..23
    const int bm = blockIdx.y;           // 0..CT-1
    const int wave = tid >> 6, lane = tid & 63;
    const int wm = wave >> 1, wn = wave & 1;
    const int lr = lane & 15, lk = lane >> 4;

    f32x4 acc[4][4] = {};

    for (int k0 = 0; k0 < D_IN; k0 += 64) {
        for (int i = tid; i < 128 * 16; i += 256) {       // A: f32->bf16
            int r = i >> 4, c4 = (i & 15) * 4;
            float4 v = *(const float4*)&x[(size_t)(bm * 128 + r) * D_IN + k0 + c4];
            unsigned short* d = &As[r][c4];
            d[0] = f2bf(v.x); d[1] = f2bf(v.y); d[2] = f2bf(v.z); d[3] = f2bf(v.w);
        }
        for (int i = tid; i < 128 * 8; i += 256) {        // B: 16B each
            int r = i >> 3, c8 = (i & 7) * 8;
            *(uint4*)&Bs[r][c8] =
                *(const uint4*)&wa[(size_t)(bn * 128 + r) * D_IN + k0 + c8];
        }
        __syncthreads();
        #pragma unroll
        for (int ks = 0; ks < 2; ++ks) {
            bf16x8 af[4], bfr[4];
            #pragma unroll
            for (int mf = 0; mf < 4; ++mf)
                af[mf] = *(const bf16x8*)&As[wm * 64 + mf * 16 + lr][ks * 32 + lk * 8];
            #pragma unroll
            for (int nf = 0; nf < 4; ++nf)
                bfr[nf] = *(const bf16x8*)&Bs[wn * 64 + nf * 16 + lr][ks * 32 + lk * 8];
            #pragma unroll
            for (int mf = 0; mf < 4; ++mf)
                #pragma unroll
                for (int nf = 0; nf < 4; ++nf)
                    acc[mf][nf] = __builtin_amdgcn_mfma_f32_16x16x32_bf16(
                        af[mf], bfr[nf], acc[mf][nf], 0, 0, 0);
        }
        __syncthreads();
    }

    #pragma unroll
    for (int nf = 0; nf < 4; ++nf) {
        int n = bn * 128 + wn * 64 + nf * 16 + lr;
        float bias = (n < 1024) ? ub[n] : ((n < 2048) ? gb[n - 1024] : 0.f);
        #pragma unroll
        for (int mf = 0; mf < 4; ++mf) {
            int mbase = bm * 128 + wm * 64 + mf * 16 + lk * 4;
            #pragma unroll
            for (int r = 0; r < 4; ++r) {
                int mrow = mbase + r;
                pre[((size_t)(mrow >> 7) * N_A + n) * 128 + (mrow & 127)] =
                    f2bf(acc[mf][nf][r] + bias);
            }
        }
    }
}

// ---------------- persistent recurrence kernel ----------------
// 256 blocks: bn = bid>>3 (32 j's), bm = bid&7 (16 b-rows). 8 waves = 8 K-slices
// of 128. wh fragments live in REGISTERS (loaded once). A-fragments loaded
// directly from hbuf via IC-coherent dwordx4 (no LDS staging). One
// __syncthreads per step (scr reduce, parity double-buffered). Per-wave
// fine-grained flag polling (8 producer flags per wave).
// NOTE rule #18: every inline-asm load + separate vmcnt(0) whose registers
// feed MFMA (non-memory op) needs sched_barrier(0) after the waitcnt.

__global__ __launch_bounds__(512, 1) void rwa_persist(
    const unsigned short* __restrict__ wh,    // [2048][1024] bf16
    const unsigned short* __restrict__ pre,   // [nt][3072][128] bf16 (this chunk)
    unsigned short* __restrict__ hbuf,        // [2][128][1024] bf16
    float* __restrict__ nbuf, float* __restrict__ dbuf,
    float* __restrict__ out,
    int* __restrict__ flags,                  // [8 bm][32 bn][2 jh]
    int t0, int nt)
{
    __shared__ float scr[2][4][7][256];       // 56 KB: [parity][tile][slot][lane*4]
    __shared__ char pad[28672];               // force 1 block/CU (total 84 KB)

    const int tid = threadIdx.x;
    const int bid = blockIdx.x;
    const int bn = bid >> 3;      // 0..31 : j-group of 32
    const int bm = bid & 7;       // 0..7  : 16 b-rows
    const int wave = tid >> 6;    // 0..7 = kq (K-slice of 128)
    const int lane = tid & 63;
    const int lr = lane & 15, lk = lane >> 4;
    const int kq = wave;

    if (t0 == -1) pad[tid] = 0;   // opaque: keep pad allocated

    // --- wh fragments -> registers (one-time, plain cached loads) ---
    bf16x8 bg0[4], ba0[4], bg1[4], ba1[4];
    {
        const int kb = kq * 128 + lk * 8;
        const unsigned short* w0 = wh + (size_t)((bn * 2 + 0) * 32 + lr) * 1024 + kb;
        const unsigned short* w1 = wh + (size_t)((bn * 2 + 1) * 32 + lr) * 1024 + kb;
        #pragma unroll
        for (int ks = 0; ks < 4; ++ks) {
            bg0[ks] = *(const bf16x8*)(w0 + ks * 32);
            ba0[ks] = *(const bf16x8*)(w0 + 16 * 1024 + ks * 32);
            bg1[ks] = *(const bf16x8*)(w1 + ks * 32);
            ba1[ks] = *(const bf16x8*)(w1 + 16 * 1024 + ks * 32);
        }
    }

    // --- epilogue geometry (waves 0,1 only; jh = wave) ---
    const int jh = wave;
    const int j  = bn * 32 + jh * 16 + lr;    // meaningful for waves 0,1
    const int bb = bm * 16 + lk * 4;
    float nr[4], dr[4];
    if (wave < 2) {
        #pragma unroll
        for (int r = 0; r < 4; ++r) {
            size_t idx = (size_t)(bb + r) * D_H + j;
            nr[r] = nbuf[idx]; dr[r] = dbuf[idx];
        }
    }

    // --- A-load base: lane covers row bm*16+lr, k = kq*128 + lk*8 (+ks*32) ---
    const unsigned short* abase0 =
        hbuf + (size_t)(bm * 16 + lr) * D_H + kq * 128 + lk * 8;
    // --- poll: 8 producer flags for this wave's K-slice ---
    const int pbn = kq * 4 + ((lane & 7) >> 1);
    const int* fp = flags + bm * 64 + pbn * 2 + (lane & 1);

    for (int l = 0; l < nt; ++l) {
        const int t = t0 + l;
        const int p = l & 1;

        // prefetch pre (plain loads; independent of h)
        u64 puL = 0, pgL = 0, paL = 0;
        if (wave < 2) {
            const unsigned short* pp = pre + (size_t)l * (N_A * 128);
            puL = *(const u64*)(pp + (size_t)j * 128 + bb);
            pgL = *(const u64*)(pp + (size_t)(1024 + j) * 128 + bb);
            paL = *(const u64*)(pp + (size_t)(2048 + j) * 128 + bb);
        }

        // wait for this K-slice's producers (per-wave, no block barrier)
        if (t > 0) {
            for (;;) {
                int v;
                asm volatile("global_load_dword %0, %1, off sc0 sc1\n\t"
                             "s_waitcnt vmcnt(0)"
                             : "=v"(v) : "v"(fp) : "memory");
                if (__all(v >= t)) break;
                __builtin_amdgcn_s_sleep(1);
            }
        }

        // A-fragments direct from IC (4 x 16B per lane)
        const unsigned short* asrc = abase0 + (size_t)(t & 1) * (NB * D_H);
        uint4 a0, a1, a2, a3;
        asm volatile("global_load_dwordx4 %0, %1, off sc0 sc1"            : "=v"(a0) : "v"(asrc) : "memory");
        asm volatile("global_load_dwordx4 %0, %1, off offset:64 sc0 sc1"  : "=v"(a1) : "v"(asrc) : "memory");
        asm volatile("global_load_dwordx4 %0, %1, off offset:128 sc0 sc1" : "=v"(a2) : "v"(asrc) : "memory");
        asm volatile("global_load_dwordx4 %0, %1, off offset:192 sc0 sc1" : "=v"(a3) : "v"(asrc) : "memory");
        asm volatile("s_waitcnt vmcnt(0)" ::: "memory");
        __builtin_amdgcn_sched_barrier(0);   // rule #18: pin MFMA after the drain

        // MFMA: 4 tiles (g/a x jh0/jh1), K-slice 128
        f32x4 ag0 = {}, aa0 = {}, ag1 = {}, aa1 = {};
        {
            bf16x8 av;
            av = cvt8(a0);
            ag0 = __builtin_amdgcn_mfma_f32_16x16x32_bf16(av, bg0[0], ag0, 0, 0, 0);
            aa0 = __builtin_amdgcn_mfma_f32_16x16x32_bf16(av, ba0[0], aa0, 0, 0, 0);
            ag1 = __builtin_amdgcn_mfma_f32_16x16x32_bf16(av, bg1[0], ag1, 0, 0, 0);
            aa1 = __builtin_amdgcn_mfma_f32_16x16x32_bf16(av, ba1[0], aa1, 0, 0, 0);
            av = cvt8(a1);
            ag0 = __builtin_amdgcn_mfma_f32_16x16x32_bf16(av, bg0[1], ag0, 0, 0, 0);
            aa0 = __builtin_amdgcn_mfma_f32_16x16x32_bf16(av, ba0[1], aa0, 0, 0, 0);
            ag1 = __builtin_amdgcn_mfma_f32_16x16x32_bf16(av, bg1[1], ag1, 0, 0, 0);
            aa1 = __builtin_amdgcn_mfma_f32_16x16x32_bf16(av, ba1[1], aa1, 0, 0, 0);
            av = cvt8(a2);
            ag0 = __builtin_amdgcn_mfma_f32_16x16x32_bf16(av, bg0[2], ag0, 0, 0, 0);
            aa0 = __builtin_amdgcn_mfma_f32_16x16x32_bf16(av, ba0[2], aa0, 0, 0, 0);
            ag1 = __builtin_amdgcn_mfma_f32_16x16x32_bf16(av, bg1[2], ag1, 0, 0, 0);
            aa1 = __builtin_amdgcn_mfma_f32_16x16x32_bf16(av, ba1[2], aa1, 0, 0, 0);
            av = cvt8(a3);
            ag0 = __builtin_amdgcn_mfma_f32_16x16x32_bf16(av, bg0[3], ag0, 0, 0, 0);
            aa0 = __builtin_amdgcn_mfma_f32_16x16x32_bf16(av, ba0[3], aa0, 0, 0, 0);
            ag1 = __builtin_amdgcn_mfma_f32_16x16x32_bf16(av, bg1[3], ag1, 0, 0, 0);
            aa1 = __builtin_amdgcn_mfma_f32_16x16x32_bf16(av, ba1[3], aa1, 0, 0, 0);
        }

        // cross-wave K reduction, parity-buffered
        if (wave == 0) {
            *(f32x4*)&scr[p][2][0][lane * 4] = ag1;
            *(f32x4*)&scr[p][3][0][lane * 4] = aa1;
        } else if (wave == 1) {
            *(f32x4*)&scr[p][0][0][lane * 4] = ag0;
            *(f32x4*)&scr[p][1][0][lane * 4] = aa0;
        } else {
            const int s = wave - 1;   // 1..6
            *(f32x4*)&scr[p][0][s][lane * 4] = ag0;
            *(f32x4*)&scr[p][1][s][lane * 4] = aa0;
            *(f32x4*)&scr[p][2][s][lane * 4] = ag1;
            *(f32x4*)&scr[p][3][s][lane * 4] = aa1;
        }
        __syncthreads();

        if (wave < 2) {
            f32x4 sg = (jh == 0) ? ag0 : ag1;
            f32x4 sa = (jh == 0) ? aa0 : aa1;
            #pragma unroll
            for (int s = 0; s < 7; ++s) {
                sg += *(const f32x4*)&scr[p][jh * 2 + 0][s][lane * 4];
                sa += *(const f32x4*)&scr[p][jh * 2 + 1][s][lane * 4];
            }

            unsigned short* hdst = hbuf + (size_t)((t + 1) & 1) * (NB * D_H);
            float hv[4];
            #pragma unroll
            for (int r = 0; r < 4; ++r) {
                float u  = bf2f((unsigned short)(puL >> (16 * r)));
                float gx = bf2f((unsigned short)(pgL >> (16 * r)));
                float ax = bf2f((unsigned short)(paL >> (16 * r)));
                float g = gx + sg[r];
                float a = ax + sa[r];
                float ea = __expf(a);
                float z = u * fast_tanh(g);
                nr[r] += z * ea;
                dr[r] += ea;
                hv[r] = fast_tanh(nr[r] / dr[r]);
                unsigned int hb = f2bf(hv[r]);
                unsigned int ob = (unsigned int)__shfl_xor((int)hb, 1);
                if (!(lr & 1)) {
                    unsigned int packed = (hb & 0xffffu) | (ob << 16);
                    unsigned short* hp = hdst + (size_t)(bb + r) * D_H + j;
                    asm volatile("global_store_dword %0, %1, off sc0 sc1"
                                 :: "v"(hp), "v"(packed) : "memory");
                }
            }
            asm volatile("s_waitcnt vmcnt(0)" ::: "memory");   // h at IC
            if (lane == 0) {
                int done = t + 1;
                asm volatile("global_store_dword %0, %1, off sc0 sc1"
                             :: "v"(flags + bm * 64 + bn * 2 + jh), "v"(done)
                             : "memory");
            }
            // out[] HBM stores off the handoff path
            #pragma unroll
            for (int r = 0; r < 4; ++r) {
                size_t idx = (size_t)(bb + r) * D_H + j;
                out[(size_t)t * (NB * D_H) + idx] = hv[r];
                if (t == T_STEPS - 1) out[(size_t)T_STEPS * (NB * D_H) + idx] = hv[r];
            }
        }
    }

    if (wave < 2) {
        #pragma unroll
        for (int r = 0; r < 4; ++r) {
            size_t idx = (size_t)(bb + r) * D_H + j;
            nbuf[idx] = nr[r]; dbuf[idx] = dr[r];
        }
    }
}

// ---------------- launch ----------------

extern "C" void kernel_launch(void* const* d_in, const int* in_sizes, int n_in,
                              void* d_out, int out_size, void* d_ws, size_t ws_size,
                              hipStream_t stream) {
    const float* x       = (const float*)d_in[0];
    const float* init_st = (const float*)d_in[1];
    const float* uW      = (const float*)d_in[2];
    const float* ub      = (const float*)d_in[3];
    const float* gW      = (const float*)d_in[4];
    const float* gb      = (const float*)d_in[5];
    const float* aW      = (const float*)d_in[6];
    float* out = (float*)d_out;

    char* ws = (char*)d_ws;
    float* nbuf = (float*)ws;                                   ws += (size_t)NB * D_H * 4;
    float* dbuf = (float*)ws;                                   ws += (size_t)NB * D_H * 4;
    unsigned short* hbuf = (unsigned short*)ws;                 ws += (size_t)2 * NB * D_H * 2;
    int* flags = (int*)ws;                                      ws += 512 * 4;
    unsigned short* wa = (unsigned short*)ws;                   ws += (size_t)N_A * D_IN * 2;
    unsigned short* wh = (unsigned short*)ws;                   ws += (size_t)N_H * D_H * 2;
    unsigned short* pre = (unsigned short*)ws;
    size_t fixed = (size_t)(ws - (char*)d_ws);
    size_t per_ct = (size_t)128 * N_A * 2;                      // 768 KB per step slot

    int CT = 1024;
    while (CT > 1 && fixed + (size_t)CT * per_ct > ws_size) CT >>= 1;

    pack_wa<<<(N_A * D_IN + 255) / 256, 256, 0, stream>>>(uW, gW, aW, wa);
    pack_wh<<<(N_H * D_H + 255) / 256, 256, 0, stream>>>(gW, aW, wh);
    rwa_init<<<(NB * D_H + 255) / 256, 256, 0, stream>>>(init_st, nbuf, dbuf, hbuf, flags);

    for (int c = 0; c < T_STEPS / CT; ++c) {
        phase_a<<<dim3(24, CT), 256, 0, stream>>>(
            x + (size_t)c * CT * NB * D_IN, wa, ub, gb, pre);
        rwa_persist<<<256, 512, 0, stream>>>(
            wh, pre, hbuf, nbuf, dbuf, out, flags, c * CT, CT);
    }
}

// Round 9
// 5671.049 us; speedup vs baseline: 1.8872x; 1.8872x over previous
//
#include <hip/hip_runtime.h>
#include <math.h>

#define T_STEPS 1024
#define NB 128
#define D_IN 512
#define D_H 1024
#define K_TOT 1536
#define N_A 3072   // packed rows: [0,1024)=uW, [1024,2048)=gW_x, [2048,3072)=aW_x
#define N_H 2048   // packed rows: group g (j in [16g,16g+16)): 16 g-rows then 16 a-rows
#define FSTRIDE 16 // flag padding: one flag per 64B cacheline

typedef __bf16 bf16x8 __attribute__((ext_vector_type(8)));
typedef float f32x4 __attribute__((ext_vector_type(4)));
typedef unsigned long long u64;

__device__ __forceinline__ unsigned short f2bf(float f) {
    unsigned int u = __float_as_uint(f);
    unsigned int r = 0x7fffu + ((u >> 16) & 1u);
    return (unsigned short)((u + r) >> 16);
}
__device__ __forceinline__ float bf2f(unsigned short v) {
    return __uint_as_float(((unsigned int)v) << 16);
}
__device__ __forceinline__ float fast_tanh(float x) {
    float ax = fabsf(x);
    float e = __expf(2.0f * ax);
    float t = 1.0f - 2.0f / (e + 1.0f);
    return copysignf(t, x);
}
__device__ __forceinline__ bf16x8 cvt8(uint4 v) {
    union { uint4 u; bf16x8 b; } c; c.u = v; return c.b;
}

// ---------------- one-time packing / init ----------------

__global__ __launch_bounds__(256) void pack_wa(
    const float* __restrict__ uW, const float* __restrict__ gW,
    const float* __restrict__ aW, unsigned short* __restrict__ wa) {
    int i = blockIdx.x * 256 + threadIdx.x;          // N_A * D_IN
    if (i >= N_A * D_IN) return;
    int rr = i >> 9, k = i & 511;
    float v;
    if (rr < 1024)       v = uW[(size_t)rr * D_IN + k];
    else if (rr < 2048)  v = gW[(size_t)(rr - 1024) * K_TOT + k];
    else                 v = aW[(size_t)(rr - 2048) * K_TOT + k];
    wa[i] = f2bf(v);
}

__global__ __launch_bounds__(256) void pack_wh(
    const float* __restrict__ gW, const float* __restrict__ aW,
    unsigned short* __restrict__ wh) {
    int i = blockIdx.x * 256 + threadIdx.x;          // N_H * D_H
    if (i >= N_H * D_H) return;
    int rr = i >> 10, k = i & 1023;
    int g = rr >> 5, ii = rr & 31, j = g * 16 + (ii & 15);
    const float* src = (ii < 16) ? gW : aW;
    wh[i] = f2bf(src[(size_t)j * K_TOT + D_IN + k]);
}

__global__ __launch_bounds__(256) void rwa_init(
    const float* __restrict__ init_st, float* __restrict__ nbuf,
    float* __restrict__ dbuf, unsigned short* __restrict__ hbuf,
    int* __restrict__ flags) {
    int i = blockIdx.x * 256 + threadIdx.x;          // NB * D_H
    if (i >= NB * D_H) return;
    nbuf[i] = 0.f; dbuf[i] = 0.f;
    hbuf[i] = f2bf(tanhf(init_st[i & (D_H - 1)]));   // parity-0 buffer
    if (i < 512 * FSTRIDE) flags[i] = 0;
}

// ---------------- phase A: pre_t = bf16( x_chunk @ W_A^T + bias ) ----------------
// output layout TRANSPOSED per step: pre[tl][n=3072][b=128] bf16

__global__ __launch_bounds__(256) void phase_a(
    const float* __restrict__ x, const unsigned short* __restrict__ wa,
    const float* __restrict__ ub, const float* __restrict__ gb,
    unsigned short* __restrict__ pre)
{
    __shared__ unsigned short As[128][72];
    __shared__ unsigned short Bs[128][72];
    const int tid = threadIdx.x;
    const int bn = blockIdx.x;           // 0..23
    const int bm = blockIdx.y;           // 0..CT-1
    const int wave = tid >> 6, lane = tid & 63;
    const int wm = wave >> 1, wn = wave & 1;
    const int lr = lane & 15, lk = lane >> 4;

    f32x4 acc[4][4] = {};

    for (int k0 = 0; k0 < D_IN; k0 += 64) {
        for (int i = tid; i < 128 * 16; i += 256) {       // A: f32->bf16
            int r = i >> 4, c4 = (i & 15) * 4;
            float4 v = *(const float4*)&x[(size_t)(bm * 128 + r) * D_IN + k0 + c4];
            unsigned short* d = &As[r][c4];
            d[0] = f2bf(v.x); d[1] = f2bf(v.y); d[2] = f2bf(v.z); d[3] = f2bf(v.w);
        }
        for (int i = tid; i < 128 * 8; i += 256) {        // B: 16B each
            int r = i >> 3, c8 = (i & 7) * 8;
            *(uint4*)&Bs[r][c8] =
                *(const uint4*)&wa[(size_t)(bn * 128 + r) * D_IN + k0 + c8];
        }
        __syncthreads();
        #pragma unroll
        for (int ks = 0; ks < 2; ++ks) {
            bf16x8 af[4], bfr[4];
            #pragma unroll
            for (int mf = 0; mf < 4; ++mf)
                af[mf] = *(const bf16x8*)&As[wm * 64 + mf * 16 + lr][ks * 32 + lk * 8];
            #pragma unroll
            for (int nf = 0; nf < 4; ++nf)
                bfr[nf] = *(const bf16x8*)&Bs[wn * 64 + nf * 16 + lr][ks * 32 + lk * 8];
            #pragma unroll
            for (int mf = 0; mf < 4; ++mf)
                #pragma unroll
                for (int nf = 0; nf < 4; ++nf)
                    acc[mf][nf] = __builtin_amdgcn_mfma_f32_16x16x32_bf16(
                        af[mf], bfr[nf], acc[mf][nf], 0, 0, 0);
        }
        __syncthreads();
    }

    #pragma unroll
    for (int nf = 0; nf < 4; ++nf) {
        int n = bn * 128 + wn * 64 + nf * 16 + lr;
        float bias = (n < 1024) ? ub[n] : ((n < 2048) ? gb[n - 1024] : 0.f);
        #pragma unroll
        for (int mf = 0; mf < 4; ++mf) {
            int mbase = bm * 128 + wm * 64 + mf * 16 + lk * 4;
            #pragma unroll
            for (int r = 0; r < 4; ++r) {
                int mrow = mbase + r;
                pre[((size_t)(mrow >> 7) * N_A + n) * 128 + (mrow & 127)] =
                    f2bf(acc[mf][nf][r] + bias);
            }
        }
    }
}

// ---------------- persistent recurrence kernel ----------------
// 256 blocks: bn = bid>>3 (32 j's), bm = bid&7 (16 b-rows). 8 waves = 8 K-slices
// of 128. wh fragments in REGISTERS; A-fragments direct from hbuf (IC-coherent).
// One __syncthreads per step. Flags: ONE PER 64B CACHELINE (no false sharing),
// polled by 8 lanes per wave only.

__global__ __launch_bounds__(512, 1) void rwa_persist(
    const unsigned short* __restrict__ wh,    // [2048][1024] bf16
    const unsigned short* __restrict__ pre,   // [nt][3072][128] bf16 (this chunk)
    unsigned short* __restrict__ hbuf,        // [2][128][1024] bf16
    float* __restrict__ nbuf, float* __restrict__ dbuf,
    float* __restrict__ out,
    int* __restrict__ flags,                  // [8 bm][32 bn][2 jh] * FSTRIDE
    int t0, int nt)
{
    __shared__ float scr[2][4][7][256];       // 56 KB: [parity][tile][slot][lane*4]

    const int tid = threadIdx.x;
    const int bid = blockIdx.x;
    const int bn = bid >> 3;      // 0..31 : j-group of 32
    const int bm = bid & 7;       // 0..7  : 16 b-rows
    const int wave = tid >> 6;    // 0..7 = kq (K-slice of 128)
    const int lane = tid & 63;
    const int lr = lane & 15, lk = lane >> 4;
    const int kq = wave;

    // --- wh fragments -> registers (one-time, plain cached loads) ---
    bf16x8 bg0[4], ba0[4], bg1[4], ba1[4];
    {
        const int kb = kq * 128 + lk * 8;
        const unsigned short* w0 = wh + (size_t)((bn * 2 + 0) * 32 + lr) * 1024 + kb;
        const unsigned short* w1 = wh + (size_t)((bn * 2 + 1) * 32 + lr) * 1024 + kb;
        #pragma unroll
        for (int ks = 0; ks < 4; ++ks) {
            bg0[ks] = *(const bf16x8*)(w0 + ks * 32);
            ba0[ks] = *(const bf16x8*)(w0 + 16 * 1024 + ks * 32);
            bg1[ks] = *(const bf16x8*)(w1 + ks * 32);
            ba1[ks] = *(const bf16x8*)(w1 + 16 * 1024 + ks * 32);
        }
    }

    // --- epilogue geometry (waves 0,1 only; jh = wave) ---
    const int jh = wave;
    const int j  = bn * 32 + jh * 16 + lr;    // meaningful for waves 0,1
    const int bb = bm * 16 + lk * 4;
    float nr[4], dr[4];
    if (wave < 2) {
        #pragma unroll
        for (int r = 0; r < 4; ++r) {
            size_t idx = (size_t)(bb + r) * D_H + j;
            nr[r] = nbuf[idx]; dr[r] = dbuf[idx];
        }
    }

    // --- A-load base: lane covers row bm*16+lr, k = kq*128 + lk*8 (+ks*32) ---
    const unsigned short* abase0 =
        hbuf + (size_t)(bm * 16 + lr) * D_H + kq * 128 + lk * 8;
    // --- poll: 8 producer flags for this wave's K-slice, lanes 0..7 only ---
    // flag index: bm*64 + bn'*2 + jh, bn' = kq*4 + (lane>>1), jh = lane&1
    const int* fp = flags + (size_t)(bm * 64 + kq * 8 + lane) * FSTRIDE;

    for (int l = 0; l < nt; ++l) {
        const int t = t0 + l;
        const int p = l & 1;

        // prefetch pre (plain loads; independent of h)
        u64 puL = 0, pgL = 0, paL = 0;
        if (wave < 2) {
            const unsigned short* pp = pre + (size_t)l * (N_A * 128);
            puL = *(const u64*)(pp + (size_t)j * 128 + bb);
            pgL = *(const u64*)(pp + (size_t)(1024 + j) * 128 + bb);
            paL = *(const u64*)(pp + (size_t)(2048 + j) * 128 + bb);
        }

        // wait for this K-slice's producers (per-wave; 8 polling lanes)
        if (t > 0) {
            for (;;) {
                int v = t;
                if (lane < 8) {
                    asm volatile("global_load_dword %0, %1, off sc0 sc1\n\t"
                                 "s_waitcnt vmcnt(0)"
                                 : "=v"(v) : "v"(fp) : "memory");
                }
                if (__all(v >= t)) break;
                __builtin_amdgcn_s_sleep(2);
            }
        }

        // A-fragments direct from IC (4 x 16B per lane)
        const unsigned short* asrc = abase0 + (size_t)(t & 1) * (NB * D_H);
        uint4 a0, a1, a2, a3;
        asm volatile("global_load_dwordx4 %0, %1, off sc0 sc1"            : "=v"(a0) : "v"(asrc) : "memory");
        asm volatile("global_load_dwordx4 %0, %1, off offset:64 sc0 sc1"  : "=v"(a1) : "v"(asrc) : "memory");
        asm volatile("global_load_dwordx4 %0, %1, off offset:128 sc0 sc1" : "=v"(a2) : "v"(asrc) : "memory");
        asm volatile("global_load_dwordx4 %0, %1, off offset:192 sc0 sc1" : "=v"(a3) : "v"(asrc) : "memory");
        asm volatile("s_waitcnt vmcnt(0)" ::: "memory");
        __builtin_amdgcn_sched_barrier(0);   // rule #18: pin MFMA after the drain

        // MFMA: 4 tiles (g/a x jh0/jh1), K-slice 128
        f32x4 ag0 = {}, aa0 = {}, ag1 = {}, aa1 = {};
        {
            bf16x8 av;
            av = cvt8(a0);
            ag0 = __builtin_amdgcn_mfma_f32_16x16x32_bf16(av, bg0[0], ag0, 0, 0, 0);
            aa0 = __builtin_amdgcn_mfma_f32_16x16x32_bf16(av, ba0[0], aa0, 0, 0, 0);
            ag1 = __builtin_amdgcn_mfma_f32_16x16x32_bf16(av, bg1[0], ag1, 0, 0, 0);
            aa1 = __builtin_amdgcn_mfma_f32_16x16x32_bf16(av, ba1[0], aa1, 0, 0, 0);
            av = cvt8(a1);
            ag0 = __builtin_amdgcn_mfma_f32_16x16x32_bf16(av, bg0[1], ag0, 0, 0, 0);
            aa0 = __builtin_amdgcn_mfma_f32_16x16x32_bf16(av, ba0[1], aa0, 0, 0, 0);
            ag1 = __builtin_amdgcn_mfma_f32_16x16x32_bf16(av, bg1[1], ag1, 0, 0, 0);
            aa1 = __builtin_amdgcn_mfma_f32_16x16x32_bf16(av, ba1[1], aa1, 0, 0, 0);
            av = cvt8(a2);
            ag0 = __builtin_amdgcn_mfma_f32_16x16x32_bf16(av, bg0[2], ag0, 0, 0, 0);
            aa0 = __builtin_amdgcn_mfma_f32_16x16x32_bf16(av, ba0[2], aa0, 0, 0, 0);
            ag1 = __builtin_amdgcn_mfma_f32_16x16x32_bf16(av, bg1[2], ag1, 0, 0, 0);
            aa1 = __builtin_amdgcn_mfma_f32_16x16x32_bf16(av, ba1[2], aa1, 0, 0, 0);
            av = cvt8(a3);
            ag0 = __builtin_amdgcn_mfma_f32_16x16x32_bf16(av, bg0[3], ag0, 0, 0, 0);
            aa0 = __builtin_amdgcn_mfma_f32_16x16x32_bf16(av, ba0[3], aa0, 0, 0, 0);
            ag1 = __builtin_amdgcn_mfma_f32_16x16x32_bf16(av, bg1[3], ag1, 0, 0, 0);
            aa1 = __builtin_amdgcn_mfma_f32_16x16x32_bf16(av, ba1[3], aa1, 0, 0, 0);
        }

        // cross-wave K reduction, parity-buffered
        if (wave == 0) {
            *(f32x4*)&scr[p][2][0][lane * 4] = ag1;
            *(f32x4*)&scr[p][3][0][lane * 4] = aa1;
        } else if (wave == 1) {
            *(f32x4*)&scr[p][0][0][lane * 4] = ag0;
            *(f32x4*)&scr[p][1][0][lane * 4] = aa0;
        } else {
            const int s = wave - 1;   // 1..6
            *(f32x4*)&scr[p][0][s][lane * 4] = ag0;
            *(f32x4*)&scr[p][1][s][lane * 4] = aa0;
            *(f32x4*)&scr[p][2][s][lane * 4] = ag1;
            *(f32x4*)&scr[p][3][s][lane * 4] = aa1;
        }
        __syncthreads();

        if (wave < 2) {
            f32x4 sg = (jh == 0) ? ag0 : ag1;
            f32x4 sa = (jh == 0) ? aa0 : aa1;
            #pragma unroll
            for (int s = 0; s < 7; ++s) {
                sg += *(const f32x4*)&scr[p][jh * 2 + 0][s][lane * 4];
                sa += *(const f32x4*)&scr[p][jh * 2 + 1][s][lane * 4];
            }

            unsigned short* hdst = hbuf + (size_t)((t + 1) & 1) * (NB * D_H);
            float hv[4];
            #pragma unroll
            for (int r = 0; r < 4; ++r) {
                float u  = bf2f((unsigned short)(puL >> (16 * r)));
                float gx = bf2f((unsigned short)(pgL >> (16 * r)));
                float ax = bf2f((unsigned short)(paL >> (16 * r)));
                float g = gx + sg[r];
                float a = ax + sa[r];
                float ea = __expf(a);
                float z = u * fast_tanh(g);
                nr[r] += z * ea;
                dr[r] += ea;
                hv[r] = fast_tanh(nr[r] / dr[r]);
                unsigned int hb = f2bf(hv[r]);
                unsigned int ob = (unsigned int)__shfl_xor((int)hb, 1);
                if (!(lr & 1)) {
                    unsigned int packed = (hb & 0xffffu) | (ob << 16);
                    unsigned short* hp = hdst + (size_t)(bb + r) * D_H + j;
                    asm volatile("global_store_dword %0, %1, off sc0 sc1"
                                 :: "v"(hp), "v"(packed) : "memory");
                }
            }
            asm volatile("s_waitcnt vmcnt(0)" ::: "memory");   // h at IC
            if (lane == 0) {
                int done = t + 1;
                const int* myflag = flags + (size_t)(bm * 64 + bn * 2 + jh) * FSTRIDE;
                asm volatile("global_store_dword %0, %1, off sc0 sc1"
                             :: "v"(myflag), "v"(done) : "memory");
            }
            // out[] HBM stores off the handoff path
            #pragma unroll
            for (int r = 0; r < 4; ++r) {
                size_t idx = (size_t)(bb + r) * D_H + j;
                out[(size_t)t * (NB * D_H) + idx] = hv[r];
                if (t == T_STEPS - 1) out[(size_t)T_STEPS * (NB * D_H) + idx] = hv[r];
            }
        }
    }

    if (wave < 2) {
        #pragma unroll
        for (int r = 0; r < 4; ++r) {
            size_t idx = (size_t)(bb + r) * D_H + j;
            nbuf[idx] = nr[r]; dbuf[idx] = dr[r];
        }
    }
}

// ---------------- launch ----------------

extern "C" void kernel_launch(void* const* d_in, const int* in_sizes, int n_in,
                              void* d_out, int out_size, void* d_ws, size_t ws_size,
                              hipStream_t stream) {
    const float* x       = (const float*)d_in[0];
    const float* init_st = (const float*)d_in[1];
    const float* uW      = (const float*)d_in[2];
    const float* ub      = (const float*)d_in[3];
    const float* gW      = (const float*)d_in[4];
    const float* gb      = (const float*)d_in[5];
    const float* aW      = (const float*)d_in[6];
    float* out = (float*)d_out;

    char* ws = (char*)d_ws;
    float* nbuf = (float*)ws;                                   ws += (size_t)NB * D_H * 4;
    float* dbuf = (float*)ws;                                   ws += (size_t)NB * D_H * 4;
    unsigned short* hbuf = (unsigned short*)ws;                 ws += (size_t)2 * NB * D_H * 2;
    int* flags = (int*)ws;                                      ws += (size_t)512 * FSTRIDE * 4;
    unsigned short* wa = (unsigned short*)ws;                   ws += (size_t)N_A * D_IN * 2;
    unsigned short* wh = (unsigned short*)ws;                   ws += (size_t)N_H * D_H * 2;
    unsigned short* pre = (unsigned short*)ws;
    size_t fixed = (size_t)(ws - (char*)d_ws);
    size_t per_ct = (size_t)128 * N_A * 2;                      // 768 KB per step slot

    int CT = 1024;
    while (CT > 1 && fixed + (size_t)CT * per_ct > ws_size) CT >>= 1;

    pack_wa<<<(N_A * D_IN + 255) / 256, 256, 0, stream>>>(uW, gW, aW, wa);
    pack_wh<<<(N_H * D_H + 255) / 256, 256, 0, stream>>>(gW, aW, wh);
    rwa_init<<<(NB * D_H + 255) / 256, 256, 0, stream>>>(init_st, nbuf, dbuf, hbuf, flags);

    for (int c = 0; c < T_STEPS / CT; ++c) {
        phase_a<<<dim3(24, CT), 256, 0, stream>>>(
            x + (size_t)c * CT * NB * D_IN, wa, ub, gb, pre);
        rwa_persist<<<256, 512, 0, stream>>>(
            wh, pre, hbuf, nbuf, dbuf, out, flags, c * CT, CT);
    }
}

// Round 11
// 5637.479 us; speedup vs baseline: 1.8985x; 1.0060x over previous
//
#include <hip/hip_runtime.h>
#include <math.h>

#define T_STEPS 1024
#define NB 128
#define D_IN 512
#define D_H 1024
#define K_TOT 1536
#define N_A 3072   // packed rows: [0,1024)=uW, [1024,2048)=gW_x, [2048,3072)=aW_x
#define N_H 2048   // packed rows: group g (j in [16g,16g+16)): 16 g-rows then 16 a-rows
#define FSTRIDE 16 // flag padding: one flag per 64B cacheline
#define LROW 1032  // padded LDS row stride (shorts)

typedef __bf16 bf16x8 __attribute__((ext_vector_type(8)));
typedef float f32x4 __attribute__((ext_vector_type(4)));
typedef unsigned long long u64;

__device__ __forceinline__ unsigned short f2bf(float f) {
    unsigned int u = __float_as_uint(f);
    unsigned int r = 0x7fffu + ((u >> 16) & 1u);
    return (unsigned short)((u + r) >> 16);
}
__device__ __forceinline__ float bf2f(unsigned short v) {
    return __uint_as_float(((unsigned int)v) << 16);
}
__device__ __forceinline__ float fast_tanh(float x) {
    float ax = fabsf(x);
    float e = __expf(2.0f * ax);
    float t = 1.0f - 2.0f / (e + 1.0f);
    return copysignf(t, x);
}

// ---------------- one-time packing / init ----------------

__global__ __launch_bounds__(256) void pack_wa(
    const float* __restrict__ uW, const float* __restrict__ gW,
    const float* __restrict__ aW, unsigned short* __restrict__ wa) {
    int i = blockIdx.x * 256 + threadIdx.x;          // N_A * D_IN
    if (i >= N_A * D_IN) return;
    int rr = i >> 9, k = i & 511;
    float v;
    if (rr < 1024)       v = uW[(size_t)rr * D_IN + k];
    else if (rr < 2048)  v = gW[(size_t)(rr - 1024) * K_TOT + k];
    else                 v = aW[(size_t)(rr - 2048) * K_TOT + k];
    wa[i] = f2bf(v);
}

__global__ __launch_bounds__(256) void pack_wh(
    const float* __restrict__ gW, const float* __restrict__ aW,
    unsigned short* __restrict__ wh) {
    int i = blockIdx.x * 256 + threadIdx.x;          // N_H * D_H
    if (i >= N_H * D_H) return;
    int rr = i >> 10, k = i & 1023;
    int g = rr >> 5, ii = rr & 31, j = g * 16 + (ii & 15);
    const float* src = (ii < 16) ? gW : aW;
    wh[i] = f2bf(src[(size_t)j * K_TOT + D_IN + k]);
}

__global__ __launch_bounds__(256) void rwa_init(
    const float* __restrict__ init_st, float* __restrict__ nbuf,
    float* __restrict__ dbuf, unsigned short* __restrict__ hbuf,
    int* __restrict__ flags) {
    int i = blockIdx.x * 256 + threadIdx.x;          // NB * D_H
    if (i >= NB * D_H) return;
    nbuf[i] = 0.f; dbuf[i] = 0.f;
    hbuf[i] = f2bf(tanhf(init_st[i & (D_H - 1)]));   // parity-0 buffer
    if (i < 512 * FSTRIDE) flags[i] = 0;
}

// ---------------- phase A: pre_t = bf16( x_chunk @ W_A^T + bias ) ----------------
// output layout TRANSPOSED per step: pre[tl][n=3072][b=128] bf16

__global__ __launch_bounds__(256) void phase_a(
    const float* __restrict__ x, const unsigned short* __restrict__ wa,
    const float* __restrict__ ub, const float* __restrict__ gb,
    unsigned short* __restrict__ pre)
{
    __shared__ unsigned short As[128][72];
    __shared__ unsigned short Bs[128][72];
    const int tid = threadIdx.x;
    const int bn = blockIdx.x;           // 0..23
    const int bm = blockIdx.y;           // 0..CT-1
    const int wave = tid >> 6, lane = tid & 63;
    const int wm = wave >> 1, wn = wave & 1;
    const int lr = lane & 15, lk = lane >> 4;

    f32x4 acc[4][4] = {};

    for (int k0 = 0; k0 < D_IN; k0 += 64) {
        for (int i = tid; i < 128 * 16; i += 256) {       // A: f32->bf16
            int r = i >> 4, c4 = (i & 15) * 4;
            float4 v = *(const float4*)&x[(size_t)(bm * 128 + r) * D_IN + k0 + c4];
            unsigned short* d = &As[r][c4];
            d[0] = f2bf(v.x); d[1] = f2bf(v.y); d[2] = f2bf(v.z); d[3] = f2bf(v.w);
        }
        for (int i = tid; i < 128 * 8; i += 256) {        // B: 16B each
            int r = i >> 3, c8 = (i & 7) * 8;
            *(uint4*)&Bs[r][c8] =
                *(const uint4*)&wa[(size_t)(bn * 128 + r) * D_IN + k0 + c8];
        }
        __syncthreads();
        #pragma unroll
        for (int ks = 0; ks < 2; ++ks) {
            bf16x8 af[4], bfr[4];
            #pragma unroll
            for (int mf = 0; mf < 4; ++mf)
                af[mf] = *(const bf16x8*)&As[wm * 64 + mf * 16 + lr][ks * 32 + lk * 8];
            #pragma unroll
            for (int nf = 0; nf < 4; ++nf)
                bfr[nf] = *(const bf16x8*)&Bs[wn * 64 + nf * 16 + lr][ks * 32 + lk * 8];
            #pragma unroll
            for (int mf = 0; mf < 4; ++mf)
                #pragma unroll
                for (int nf = 0; nf < 4; ++nf)
                    acc[mf][nf] = __builtin_amdgcn_mfma_f32_16x16x32_bf16(
                        af[mf], bfr[nf], acc[mf][nf], 0, 0, 0);
        }
        __syncthreads();
    }

    #pragma unroll
    for (int nf = 0; nf < 4; ++nf) {
        int n = bn * 128 + wn * 64 + nf * 16 + lr;
        float bias = (n < 1024) ? ub[n] : ((n < 2048) ? gb[n - 1024] : 0.f);
        #pragma unroll
        for (int mf = 0; mf < 4; ++mf) {
            int mbase = bm * 128 + wm * 64 + mf * 16 + lk * 4;
            #pragma unroll
            for (int r = 0; r < 4; ++r) {
                int mrow = mbase + r;
                pre[((size_t)(mrow >> 7) * N_A + n) * 128 + (mrow & 127)] =
                    f2bf(acc[mf][nf][r] + bias);
            }
        }
    }
}

// ---------------- persistent recurrence kernel (full-K per wave) ----------------
// 128 blocks: bn = bid>>3 (64 j's), bm = bid&7 (16 b-rows). 4 waves; wave w owns
// j-group bn*4+w, computing BOTH g and a over the FULL K=1024 -> no cross-wave
// reduction, wave-local epilogue. Weights in VGPRs (256/wave). h tile 16x1024
// staged to LDS (parity double-buffer; 8x16B per thread = FULL 2048B rows),
// ONE __syncthreads per step.

__global__ __launch_bounds__(256, 1) void rwa_persist(
    const unsigned short* __restrict__ wh,    // [2048][1024] bf16
    const unsigned short* __restrict__ pre,   // [nt][3072][128] bf16 (this chunk)
    unsigned short* __restrict__ hbuf,        // [2][128][1024] bf16
    float* __restrict__ nbuf, float* __restrict__ dbuf,
    float* __restrict__ out,
    int* __restrict__ flags,                  // [8 bm][64 jgrp] * FSTRIDE
    int t0, int nt)
{
    __shared__ unsigned short hs[2][16][LROW];   // 66 KB

    const int tid = threadIdx.x;
    const int bid = blockIdx.x;
    const int bn = bid >> 3;      // 0..15 : j-base bn*64
    const int bm = bid & 7;       // 0..7  : b-base bm*16
    const int wave = tid >> 6;    // 0..3  : j-group within block
    const int lane = tid & 63;
    const int lr = lane & 15, lk = lane >> 4;

    // --- weights -> 256 VGPRs (one-time, plain cached loads) ---
    bf16x8 bg[32], ba[32];
    {
        const unsigned short* wb =
            wh + ((size_t)(bn * 4 + wave) * 32 + lr) * 1024 + lk * 8;
        #pragma unroll
        for (int kf = 0; kf < 32; ++kf) {
            bg[kf] = *(const bf16x8*)(wb + kf * 32);
            ba[kf] = *(const bf16x8*)(wb + 16 * 1024 + kf * 32);
        }
    }

    const int j  = bn * 64 + wave * 16 + lr;
    const int bb = bm * 16 + lk * 4;
    float nr[4], dr[4];
    #pragma unroll
    for (int r = 0; r < 4; ++r) {
        size_t idx = (size_t)(bb + r) * D_H + j;
        nr[r] = nbuf[idx]; dr[r] = dbuf[idx];
    }

    // staging geometry: thread -> row sr, granules sg+16i (i=0..7), 16B each
    // -> 16 threads/row x 8 x 16B = full 2048B row
    const int sr = tid >> 4;          // 0..15
    const int sg = tid & 15;
    const unsigned short* hsrc0 = hbuf + (size_t)(bm * 16 + sr) * D_H + sg * 8;
    const int* fp = flags + (size_t)(bm * 64 + lane) * FSTRIDE;   // 64 producers
    int* const myflag = flags + (size_t)(bm * 64 + bn * 4 + wave) * FSTRIDE;

    for (int l = 0; l < nt; ++l) {
        const int t = t0 + l;
        const int p = t & 1;

        // prefetch pre (independent of h; hides HBM latency)
        u64 puL, pgL, paL;
        {
            const unsigned short* pp = pre + (size_t)l * (N_A * 128);
            puL = *(const u64*)(pp + (size_t)j * 128 + bb);
            pgL = *(const u64*)(pp + (size_t)(1024 + j) * 128 + bb);
            paL = *(const u64*)(pp + (size_t)(2048 + j) * 128 + bb);
        }

        // wait for all 64 producer-waves of this bm group (1 flag per lane)
        if (t > 0) {
            for (;;) {
                int v;
                asm volatile("global_load_dword %0, %1, off sc0 sc1\n\t"
                             "s_waitcnt vmcnt(0)"
                             : "=v"(v) : "v"(fp) : "memory");
                if (__all(v >= t)) break;
                __builtin_amdgcn_s_sleep(2);
            }
        }

        // stage h tile 16x1024 into hs[p] (8 x dwordx4 per thread = full rows)
        {
            const unsigned short* hsrc = hsrc0 + (size_t)p * (NB * D_H);
            uint4 v0, v1, v2, v3, v4, v5, v6, v7;
            asm volatile("global_load_dwordx4 %0, %1, off sc0 sc1"             : "=v"(v0) : "v"(hsrc) : "memory");
            asm volatile("global_load_dwordx4 %0, %1, off offset:256 sc0 sc1"  : "=v"(v1) : "v"(hsrc) : "memory");
            asm volatile("global_load_dwordx4 %0, %1, off offset:512 sc0 sc1"  : "=v"(v2) : "v"(hsrc) : "memory");
            asm volatile("global_load_dwordx4 %0, %1, off offset:768 sc0 sc1"  : "=v"(v3) : "v"(hsrc) : "memory");
            asm volatile("global_load_dwordx4 %0, %1, off offset:1024 sc0 sc1" : "=v"(v4) : "v"(hsrc) : "memory");
            asm volatile("global_load_dwordx4 %0, %1, off offset:1280 sc0 sc1" : "=v"(v5) : "v"(hsrc) : "memory");
            asm volatile("global_load_dwordx4 %0, %1, off offset:1536 sc0 sc1" : "=v"(v6) : "v"(hsrc) : "memory");
            asm volatile("global_load_dwordx4 %0, %1, off offset:1792 sc0 sc1" : "=v"(v7) : "v"(hsrc) : "memory");
            asm volatile("s_waitcnt vmcnt(0)" ::: "memory");
            *(uint4*)&hs[p][sr][(sg +   0) * 8] = v0;
            *(uint4*)&hs[p][sr][(sg +  16) * 8] = v1;
            *(uint4*)&hs[p][sr][(sg +  32) * 8] = v2;
            *(uint4*)&hs[p][sr][(sg +  48) * 8] = v3;
            *(uint4*)&hs[p][sr][(sg +  64) * 8] = v4;
            *(uint4*)&hs[p][sr][(sg +  80) * 8] = v5;
            *(uint4*)&hs[p][sr][(sg +  96) * 8] = v6;
            *(uint4*)&hs[p][sr][(sg + 112) * 8] = v7;
        }
        __syncthreads();   // hs[p] ready; parity + flag transitivity protect WAR

        // MFMA: full K=1024, both mats, 4 interleaved chains
        f32x4 g0 = {}, g1 = {}, a0 = {}, a1 = {};
        #pragma unroll
        for (int kf = 0; kf < 32; kf += 2) {
            bf16x8 av0 = *(const bf16x8*)&hs[p][lr][kf * 32 + lk * 8];
            bf16x8 av1 = *(const bf16x8*)&hs[p][lr][(kf + 1) * 32 + lk * 8];
            g0 = __builtin_amdgcn_mfma_f32_16x16x32_bf16(av0, bg[kf],     g0, 0, 0, 0);
            a0 = __builtin_amdgcn_mfma_f32_16x16x32_bf16(av0, ba[kf],     a0, 0, 0, 0);
            g1 = __builtin_amdgcn_mfma_f32_16x16x32_bf16(av1, bg[kf + 1], g1, 0, 0, 0);
            a1 = __builtin_amdgcn_mfma_f32_16x16x32_bf16(av1, ba[kf + 1], a1, 0, 0, 0);
        }
        const f32x4 sgv = g0 + g1;
        const f32x4 sav = a0 + a1;

        // wave-local epilogue
        unsigned short* hdst = hbuf + (size_t)((t + 1) & 1) * (NB * D_H);
        float hv[4];
        #pragma unroll
        for (int r = 0; r < 4; ++r) {
            float u  = bf2f((unsigned short)(puL >> (16 * r)));
            float gx = bf2f((unsigned short)(pgL >> (16 * r)));
            float ax = bf2f((unsigned short)(paL >> (16 * r)));
            float g = gx + sgv[r];
            float a = ax + sav[r];
            float ea = __expf(a);
            float z = u * fast_tanh(g);
            nr[r] += z * ea;
            dr[r] += ea;
            hv[r] = fast_tanh(nr[r] / dr[r]);
            unsigned int hb = f2bf(hv[r]);
            unsigned int ob = (unsigned int)__shfl_xor((int)hb, 1);
            if (!(lr & 1)) {
                unsigned int packed = (hb & 0xffffu) | (ob << 16);
                unsigned short* hp = hdst + (size_t)(bb + r) * D_H + j;
                asm volatile("global_store_dword %0, %1, off sc0 sc1"
                             :: "v"(hp), "v"(packed) : "memory");
            }
        }
        asm volatile("s_waitcnt vmcnt(0)" ::: "memory");   // h visible at L3
        if (lane == 0) {
            int done = t + 1;
            asm volatile("global_store_dword %0, %1, off sc0 sc1"
                         :: "v"(myflag), "v"(done) : "memory");
        }
        // out[] HBM stores off the handoff path
        #pragma unroll
        for (int r = 0; r < 4; ++r) {
            size_t idx = (size_t)(bb + r) * D_H + j;
            out[(size_t)t * (NB * D_H) + idx] = hv[r];
            if (t == T_STEPS - 1) out[(size_t)T_STEPS * (NB * D_H) + idx] = hv[r];
        }
    }

    // chunk end: spill n/d
    #pragma unroll
    for (int r = 0; r < 4; ++r) {
        size_t idx = (size_t)(bb + r) * D_H + j;
        nbuf[idx] = nr[r]; dbuf[idx] = dr[r];
    }
}

// ---------------- launch ----------------

extern "C" void kernel_launch(void* const* d_in, const int* in_sizes, int n_in,
                              void* d_out, int out_size, void* d_ws, size_t ws_size,
                              hipStream_t stream) {
    const float* x       = (const float*)d_in[0];
    const float* init_st = (const float*)d_in[1];
    const float* uW      = (const float*)d_in[2];
    const float* ub      = (const float*)d_in[3];
    const float* gW      = (const float*)d_in[4];
    const float* gb      = (const float*)d_in[5];
    const float* aW      = (const float*)d_in[6];
    float* out = (float*)d_out;

    char* ws = (char*)d_ws;
    float* nbuf = (float*)ws;                                   ws += (size_t)NB * D_H * 4;
    float* dbuf = (float*)ws;                                   ws += (size_t)NB * D_H * 4;
    unsigned short* hbuf = (unsigned short*)ws;                 ws += (size_t)2 * NB * D_H * 2;
    int* flags = (int*)ws;                                      ws += (size_t)512 * FSTRIDE * 4;
    unsigned short* wa = (unsigned short*)ws;                   ws += (size_t)N_A * D_IN * 2;
    unsigned short* wh = (unsigned short*)ws;                   ws += (size_t)N_H * D_H * 2;
    unsigned short* pre = (unsigned short*)ws;
    size_t fixed = (size_t)(ws - (char*)d_ws);
    size_t per_ct = (size_t)128 * N_A * 2;                      // 768 KB per step slot

    int CT = 1024;
    while (CT > 1 && fixed + (size_t)CT * per_ct > ws_size) CT >>= 1;

    pack_wa<<<(N_A * D_IN + 255) / 256, 256, 0, stream>>>(uW, gW, aW, wa);
    pack_wh<<<(N_H * D_H + 255) / 256, 256, 0, stream>>>(gW, aW, wh);
    rwa_init<<<(NB * D_H + 255) / 256, 256, 0, stream>>>(init_st, nbuf, dbuf, hbuf, flags);

    for (int c = 0; c < T_STEPS / CT; ++c) {
        phase_a<<<dim3(24, CT), 256, 0, stream>>>(
            x + (size_t)c * CT * NB * D_IN, wa, ub, gb, pre);
        rwa_persist<<<128, 256, 0, stream>>>(
            wh, pre, hbuf, nbuf, dbuf, out, flags, c * CT, CT);
    }
}

// Round 13
// 5601.414 us; speedup vs baseline: 1.9107x; 1.0064x over previous
//
#include <hip/hip_runtime.h>
#include <math.h>

#define T_STEPS 1024
#define NB 128
#define D_IN 512
#define D_H 1024
#define K_TOT 1536
#define N_A 3072   // packed rows: [0,1024)=uW, [1024,2048)=gW_x, [2048,3072)=aW_x
#define N_H 2048   // packed rows: group g (j in [16g,16g+16)): 16 g-rows then 16 a-rows
#define FSTRIDE 16 // flag padding: one flag per 64B cacheline
#define LROW 1032  // padded LDS row stride (shorts)

typedef __bf16 bf16x8 __attribute__((ext_vector_type(8)));
typedef float f32x4 __attribute__((ext_vector_type(4)));
typedef unsigned long long u64;

__device__ __forceinline__ unsigned short f2bf(float f) {
    unsigned int u = __float_as_uint(f);
    unsigned int r = 0x7fffu + ((u >> 16) & 1u);
    return (unsigned short)((u + r) >> 16);
}
__device__ __forceinline__ float bf2f(unsigned short v) {
    return __uint_as_float(((unsigned int)v) << 16);
}
__device__ __forceinline__ float fast_tanh(float x) {
    float ax = fabsf(x);
    float e = __expf(2.0f * ax);
    float t = 1.0f - 2.0f / (e + 1.0f);
    return copysignf(t, x);
}

// ---------------- one-time packing / init ----------------

__global__ __launch_bounds__(256) void pack_wa(
    const float* __restrict__ uW, const float* __restrict__ gW,
    const float* __restrict__ aW, unsigned short* __restrict__ wa) {
    int i = blockIdx.x * 256 + threadIdx.x;          // N_A * D_IN
    if (i >= N_A * D_IN) return;
    int rr = i >> 9, k = i & 511;
    float v;
    if (rr < 1024)       v = uW[(size_t)rr * D_IN + k];
    else if (rr < 2048)  v = gW[(size_t)(rr - 1024) * K_TOT + k];
    else                 v = aW[(size_t)(rr - 2048) * K_TOT + k];
    wa[i] = f2bf(v);
}

__global__ __launch_bounds__(256) void pack_wh(
    const float* __restrict__ gW, const float* __restrict__ aW,
    unsigned short* __restrict__ wh) {
    int i = blockIdx.x * 256 + threadIdx.x;          // N_H * D_H
    if (i >= N_H * D_H) return;
    int rr = i >> 10, k = i & 1023;
    int g = rr >> 5, ii = rr & 31, j = g * 16 + (ii & 15);
    const float* src = (ii < 16) ? gW : aW;
    wh[i] = f2bf(src[(size_t)j * K_TOT + D_IN + k]);
}

__global__ __launch_bounds__(256) void pack_x(
    const float* __restrict__ x, unsigned short* __restrict__ xb, int nq) {
    // nq = element count / 4
    for (int i = blockIdx.x * 256 + threadIdx.x; i < nq; i += gridDim.x * 256) {
        float4 v = ((const float4*)x)[i];
        ushort4 o;
        o.x = f2bf(v.x); o.y = f2bf(v.y); o.z = f2bf(v.z); o.w = f2bf(v.w);
        ((ushort4*)xb)[i] = o;
    }
}

__global__ __launch_bounds__(256) void rwa_init(
    const float* __restrict__ init_st, float* __restrict__ nbuf,
    float* __restrict__ dbuf, unsigned short* __restrict__ hbuf,
    int* __restrict__ flags) {
    int i = blockIdx.x * 256 + threadIdx.x;          // NB * D_H
    if (i >= NB * D_H) return;
    nbuf[i] = 0.f; dbuf[i] = 0.f;
    hbuf[i] = f2bf(tanhf(init_st[i & (D_H - 1)]));   // parity-0 buffer
    if (i < 512 * FSTRIDE) flags[i] = 0;
}

// ---------------- phase A: pre_t = bf16( xb_chunk @ W_A^T + bias ) ----------------
// xb: [CT*128, 512] bf16 (pre-converted); output TRANSPOSED: pre[tl][3072][128]

__global__ __launch_bounds__(256) void phase_a(
    const unsigned short* __restrict__ xb, const unsigned short* __restrict__ wa,
    const float* __restrict__ ub, const float* __restrict__ gb,
    unsigned short* __restrict__ pre)
{
    __shared__ unsigned short As[128][72];
    __shared__ unsigned short Bs[128][72];
    const int tid = threadIdx.x;
    const int bn = blockIdx.x;           // 0..23
    const int bm = blockIdx.y;           // 0..CT-1
    const int wave = tid >> 6, lane = tid & 63;
    const int wm = wave >> 1, wn = wave & 1;
    const int lr = lane & 15, lk = lane >> 4;

    f32x4 acc[4][4] = {};

    for (int k0 = 0; k0 < D_IN; k0 += 64) {
        for (int i = tid; i < 128 * 8; i += 256) {        // A: 16B each (bf16)
            int r = i >> 3, c8 = (i & 7) * 8;
            *(uint4*)&As[r][c8] =
                *(const uint4*)&xb[(size_t)(bm * 128 + r) * D_IN + k0 + c8];
        }
        for (int i = tid; i < 128 * 8; i += 256) {        // B: 16B each
            int r = i >> 3, c8 = (i & 7) * 8;
            *(uint4*)&Bs[r][c8] =
                *(const uint4*)&wa[(size_t)(bn * 128 + r) * D_IN + k0 + c8];
        }
        __syncthreads();
        #pragma unroll
        for (int ks = 0; ks < 2; ++ks) {
            bf16x8 af[4], bfr[4];
            #pragma unroll
            for (int mf = 0; mf < 4; ++mf)
                af[mf] = *(const bf16x8*)&As[wm * 64 + mf * 16 + lr][ks * 32 + lk * 8];
            #pragma unroll
            for (int nf = 0; nf < 4; ++nf)
                bfr[nf] = *(const bf16x8*)&Bs[wn * 64 + nf * 16 + lr][ks * 32 + lk * 8];
            #pragma unroll
            for (int mf = 0; mf < 4; ++mf)
                #pragma unroll
                for (int nf = 0; nf < 4; ++nf)
                    acc[mf][nf] = __builtin_amdgcn_mfma_f32_16x16x32_bf16(
                        af[mf], bfr[nf], acc[mf][nf], 0, 0, 0);
        }
        __syncthreads();
    }

    #pragma unroll
    for (int nf = 0; nf < 4; ++nf) {
        int n = bn * 128 + wn * 64 + nf * 16 + lr;
        float bias = (n < 1024) ? ub[n] : ((n < 2048) ? gb[n - 1024] : 0.f);
        #pragma unroll
        for (int mf = 0; mf < 4; ++mf) {
            int mbase = bm * 128 + wm * 64 + mf * 16 + lk * 4;
            #pragma unroll
            for (int r = 0; r < 4; ++r) {
                int mrow = mbase + r;
                pre[((size_t)(mrow >> 7) * N_A + n) * 128 + (mrow & 127)] =
                    f2bf(acc[mf][nf][r] + bias);
            }
        }
    }
}

// ---------------- persistent recurrence kernel (full-K per wave) ----------------
// 128 blocks: bn = bid>>3 (64 j's), bm = bid&7 (16 b-rows). 4 waves; wave w owns
// j-group bn*4+w over FULL K=1024. Weights in VGPRs. h staged to LDS (parity
// dbuf). Handoff: ONE flag PER BLOCK (16 polled lines/group, 16 lanes polling
// — 4x less L3 poll traffic than per-wave flags). pre loads issued AFTER poll
// success so the poll's vmcnt(0) never drains them (overlap under stage+MFMA).

__global__ __launch_bounds__(256, 1) void rwa_persist(
    const unsigned short* __restrict__ wh,    // [2048][1024] bf16
    const unsigned short* __restrict__ pre,   // [nt][3072][128] bf16 (this chunk)
    unsigned short* __restrict__ hbuf,        // [2][128][1024] bf16
    float* __restrict__ nbuf, float* __restrict__ dbuf,
    float* __restrict__ out,
    int* __restrict__ flags,                  // [8 bm][16 bn] * FSTRIDE
    int t0, int nt)
{
    __shared__ unsigned short hs[2][16][LROW];   // 66 KB

    const int tid = threadIdx.x;
    const int bid = blockIdx.x;
    const int bn = bid >> 3;      // 0..15 : j-base bn*64
    const int bm = bid & 7;       // 0..7  : b-base bm*16
    const int wave = tid >> 6;    // 0..3  : j-group within block
    const int lane = tid & 63;
    const int lr = lane & 15, lk = lane >> 4;

    // --- weights -> 256 VGPRs (one-time, plain cached loads) ---
    bf16x8 bg[32], ba[32];
    {
        const unsigned short* wb =
            wh + ((size_t)(bn * 4 + wave) * 32 + lr) * 1024 + lk * 8;
        #pragma unroll
        for (int kf = 0; kf < 32; ++kf) {
            bg[kf] = *(const bf16x8*)(wb + kf * 32);
            ba[kf] = *(const bf16x8*)(wb + 16 * 1024 + kf * 32);
        }
    }

    const int j  = bn * 64 + wave * 16 + lr;
    const int bb = bm * 16 + lk * 4;
    float nr[4], dr[4];
    #pragma unroll
    for (int r = 0; r < 4; ++r) {
        size_t idx = (size_t)(bb + r) * D_H + j;
        nr[r] = nbuf[idx]; dr[r] = dbuf[idx];
    }

    // staging geometry: thread -> row sr, granules sg+16i (i=0..7), 16B each
    const int sr = tid >> 4;          // 0..15
    const int sg = tid & 15;
    const unsigned short* hsrc0 = hbuf + (size_t)(bm * 16 + sr) * D_H + sg * 8;
    const int* fp = flags + (size_t)(bm * 16 + (lane & 15)) * FSTRIDE;  // 16 producers
    int* const myflag = flags + (size_t)(bm * 16 + bn) * FSTRIDE;

    for (int l = 0; l < nt; ++l) {
        const int t = t0 + l;
        const int p = t & 1;

        // --- wait for all 16 producer BLOCKS of this bm group (16 lanes poll) ---
        if (t > 0) {
            for (;;) {
                int v = t;
                if (lane < 16) {
                    asm volatile("global_load_dword %0, %1, off sc0 sc1\n\t"
                                 "s_waitcnt vmcnt(0)"
                                 : "=v"(v) : "v"(fp) : "memory");
                }
                if (__all(v >= t)) break;
                __builtin_amdgcn_s_sleep(1);
            }
        }

        // --- pre loads issued NOW (hide under stage + barrier + MFMA) ---
        u64 puL, pgL, paL;
        {
            const unsigned short* pp = pre + (size_t)l * (N_A * 128);
            puL = *(const u64*)(pp + (size_t)j * 128 + bb);
            pgL = *(const u64*)(pp + (size_t)(1024 + j) * 128 + bb);
            paL = *(const u64*)(pp + (size_t)(2048 + j) * 128 + bb);
        }

        // --- stage h tile 16x1024 into hs[p] (8 x dwordx4 per thread) ---
        {
            const unsigned short* hsrc = hsrc0 + (size_t)p * (NB * D_H);
            uint4 v0, v1, v2, v3, v4, v5, v6, v7;
            asm volatile("global_load_dwordx4 %0, %1, off sc0 sc1"             : "=v"(v0) : "v"(hsrc) : "memory");
            asm volatile("global_load_dwordx4 %0, %1, off offset:256 sc0 sc1"  : "=v"(v1) : "v"(hsrc) : "memory");
            asm volatile("global_load_dwordx4 %0, %1, off offset:512 sc0 sc1"  : "=v"(v2) : "v"(hsrc) : "memory");
            asm volatile("global_load_dwordx4 %0, %1, off offset:768 sc0 sc1"  : "=v"(v3) : "v"(hsrc) : "memory");
            asm volatile("global_load_dwordx4 %0, %1, off offset:1024 sc0 sc1" : "=v"(v4) : "v"(hsrc) : "memory");
            asm volatile("global_load_dwordx4 %0, %1, off offset:1280 sc0 sc1" : "=v"(v5) : "v"(hsrc) : "memory");
            asm volatile("global_load_dwordx4 %0, %1, off offset:1536 sc0 sc1" : "=v"(v6) : "v"(hsrc) : "memory");
            asm volatile("global_load_dwordx4 %0, %1, off offset:1792 sc0 sc1" : "=v"(v7) : "v"(hsrc) : "memory");
            asm volatile("s_waitcnt vmcnt(0)" ::: "memory");
            *(uint4*)&hs[p][sr][(sg +   0) * 8] = v0;
            *(uint4*)&hs[p][sr][(sg +  16) * 8] = v1;
            *(uint4*)&hs[p][sr][(sg +  32) * 8] = v2;
            *(uint4*)&hs[p][sr][(sg +  48) * 8] = v3;
            *(uint4*)&hs[p][sr][(sg +  64) * 8] = v4;
            *(uint4*)&hs[p][sr][(sg +  80) * 8] = v5;
            *(uint4*)&hs[p][sr][(sg +  96) * 8] = v6;
            *(uint4*)&hs[p][sr][(sg + 112) * 8] = v7;
        }
        __syncthreads();   // hs[p] ready; parity + flag transitivity protect WAR

        // MFMA: full K=1024, both mats, 4 interleaved chains
        f32x4 g0 = {}, g1 = {}, a0 = {}, a1 = {};
        #pragma unroll
        for (int kf = 0; kf < 32; kf += 2) {
            bf16x8 av0 = *(const bf16x8*)&hs[p][lr][kf * 32 + lk * 8];
            bf16x8 av1 = *(const bf16x8*)&hs[p][lr][(kf + 1) * 32 + lk * 8];
            g0 = __builtin_amdgcn_mfma_f32_16x16x32_bf16(av0, bg[kf],     g0, 0, 0, 0);
            a0 = __builtin_amdgcn_mfma_f32_16x16x32_bf16(av0, ba[kf],     a0, 0, 0, 0);
            g1 = __builtin_amdgcn_mfma_f32_16x16x32_bf16(av1, bg[kf + 1], g1, 0, 0, 0);
            a1 = __builtin_amdgcn_mfma_f32_16x16x32_bf16(av1, ba[kf + 1], a1, 0, 0, 0);
        }
        const f32x4 sgv = g0 + g1;
        const f32x4 sav = a0 + a1;

        // wave-local epilogue
        unsigned short* hdst = hbuf + (size_t)((t + 1) & 1) * (NB * D_H);
        float hv[4];
        #pragma unroll
        for (int r = 0; r < 4; ++r) {
            float u  = bf2f((unsigned short)(puL >> (16 * r)));
            float gx = bf2f((unsigned short)(pgL >> (16 * r)));
            float ax = bf2f((unsigned short)(paL >> (16 * r)));
            float g = gx + sgv[r];
            float a = ax + sav[r];
            float ea = __expf(a);
            float z = u * fast_tanh(g);
            nr[r] += z * ea;
            dr[r] += ea;
            hv[r] = fast_tanh(nr[r] / dr[r]);
            unsigned int hb = f2bf(hv[r]);
            unsigned int ob = (unsigned int)__shfl_xor((int)hb, 1);
            if (!(lr & 1)) {
                unsigned int packed = (hb & 0xffffu) | (ob << 16);
                unsigned short* hp = hdst + (size_t)(bb + r) * D_H + j;
                asm volatile("global_store_dword %0, %1, off sc0 sc1"
                             :: "v"(hp), "v"(packed) : "memory");
            }
        }
        asm volatile("s_waitcnt vmcnt(0)" ::: "memory");   // this wave's h at L3
        __syncthreads();                                   // all waves' h acked
        if (tid == 0) {
            int done = t + 1;
            asm volatile("global_store_dword %0, %1, off sc0 sc1"
                         :: "v"(myflag), "v"(done) : "memory");
        }
        // out[] HBM stores off the handoff path (drain during next poll)
        #pragma unroll
        for (int r = 0; r < 4; ++r) {
            size_t idx = (size_t)(bb + r) * D_H + j;
            out[(size_t)t * (NB * D_H) + idx] = hv[r];
            if (t == T_STEPS - 1) out[(size_t)T_STEPS * (NB * D_H) + idx] = hv[r];
        }
    }

    // chunk end: spill n/d
    #pragma unroll
    for (int r = 0; r < 4; ++r) {
        size_t idx = (size_t)(bb + r) * D_H + j;
        nbuf[idx] = nr[r]; dbuf[idx] = dr[r];
    }
}

// ---------------- launch ----------------

extern "C" void kernel_launch(void* const* d_in, const int* in_sizes, int n_in,
                              void* d_out, int out_size, void* d_ws, size_t ws_size,
                              hipStream_t stream) {
    const float* x       = (const float*)d_in[0];
    const float* init_st = (const float*)d_in[1];
    const float* uW      = (const float*)d_in[2];
    const float* ub      = (const float*)d_in[3];
    const float* gW      = (const float*)d_in[4];
    const float* gb      = (const float*)d_in[5];
    const float* aW      = (const float*)d_in[6];
    float* out = (float*)d_out;

    char* ws = (char*)d_ws;
    float* nbuf = (float*)ws;                                   ws += (size_t)NB * D_H * 4;
    float* dbuf = (float*)ws;                                   ws += (size_t)NB * D_H * 4;
    unsigned short* hbuf = (unsigned short*)ws;                 ws += (size_t)2 * NB * D_H * 2;
    int* flags = (int*)ws;                                      ws += (size_t)512 * FSTRIDE * 4;
    unsigned short* wa = (unsigned short*)ws;                   ws += (size_t)N_A * D_IN * 2;
    unsigned short* wh = (unsigned short*)ws;                   ws += (size_t)N_H * D_H * 2;
    unsigned short* pre = (unsigned short*)ws;
    size_t fixed = (size_t)(ws - (char*)d_ws);
    // per step slot: pre (768 KB) + xb (128 KB)
    size_t per_ct = (size_t)128 * N_A * 2 + (size_t)NB * D_IN * 2;

    int CT = 1024;
    while (CT > 1 && fixed + (size_t)CT * per_ct > ws_size) CT >>= 1;
    unsigned short* xb = pre + (size_t)CT * 128 * N_A;

    pack_wa<<<(N_A * D_IN + 255) / 256, 256, 0, stream>>>(uW, gW, aW, wa);
    pack_wh<<<(N_H * D_H + 255) / 256, 256, 0, stream>>>(gW, aW, wh);
    rwa_init<<<(NB * D_H + 255) / 256, 256, 0, stream>>>(init_st, nbuf, dbuf, hbuf, flags);

    for (int c = 0; c < T_STEPS / CT; ++c) {
        int nq = CT * NB * D_IN / 4;
        pack_x<<<2048, 256, 0, stream>>>(x + (size_t)c * CT * NB * D_IN, xb, nq);
        phase_a<<<dim3(24, CT), 256, 0, stream>>>(xb, wa, ub, gb, pre);
        rwa_persist<<<128, 256, 0, stream>>>(
            wh, pre, hbuf, nbuf, dbuf, out, flags, c * CT, CT);
    }
}